// Round 7
// baseline (246.707 us; speedup 1.0000x reference)
//
#include <hip/hip_runtime.h>

// ROI bilinear pooling (tf.image.resize half-pixel centers), POOL=7.
// img: (1, 64, 64, 1024) fp32 NHWC. rois: (1, R, 4) int32 = [x, y, w, h].
// out: (1, R, 7, 7, 1024) fp32.
//
// R6 = R3 LDS-dedup retested WITHOUT the confounders:
//  - GROUP 64->32 channels: 32 KB LDS/block -> 5 blocks/CU (R3: 64KB -> 2),
//    so stage(DMA) and compute(LDS) phases of different blocks overlap on a CU.
//  - plain stores (R4 lesson: NT costs ~3.5-9 us).
// Structural read dedup: each unique (pixel, channel-slice) byte fetched from
// global exactly once -> 822 MB logical reads become 295 MB, independent of
// cache/dispatch luck. Theory: kernel is Infinity-Cache-read-bound (~8 TB/s).

#define POOLSZ 7
#define IMG_W 64
#define IMG_C 1024
#define GROUP 32               // channels per block
#define NQUAD (GROUP / 4)      // 8 float4 per pixel slice
#define NGROUP (IMG_C / GROUP) // 32 blocks per ROI
#define MAXPX 256              // 16x16 max box
#define NUM_XCD 8

typedef float v4f __attribute__((ext_vector_type(4)));
typedef __attribute__((address_space(1))) const void as1_cvoid;
typedef __attribute__((address_space(3))) void as3_void;

__global__ __launch_bounds__(256, 4) void roi_pool_lds32_kernel(
    const float* __restrict__ img,
    const int* __restrict__ rois,
    float* __restrict__ out,
    int roisPerXcd) {          // R/8 when R%8==0, else 0 (identity mapping)

    __shared__ v4f smem[MAXPX * NQUAD];   // 32 KB

    int r, g;
    if (roisPerXcd > 0) {
        // xcd = blockIdx % 8; all 32 channel-blocks of an ROI chunk -> one XCD.
        const int xcd   = blockIdx.x & (NUM_XCD - 1);
        const int local = blockIdx.x >> 3;            // 0 .. R/8*32-1
        r = xcd * roisPerXcd + (local >> 5);
        g = local & (NGROUP - 1);
    } else {
        r = blockIdx.x >> 5;
        g = blockIdx.x & (NGROUP - 1);
    }

    const int4 roi = ((const int4*)rois)[r];
    const int rx = roi.x, ry = roi.y, rw = roi.z, rh = roi.w;
    const int npx   = rw * rh;            // <= 256
    const int total = npx * NQUAD;        // float4s to stage, <= 2048

    // exact small-range div-by-rw: p/rw == (p*magic)>>16 for p<=255, rw<=16
    const unsigned magic = (65536u + (unsigned)rw - 1u) / (unsigned)rw;

    const float* src0 = img + ((size_t)ry * IMG_W + rx) * IMG_C + g * GROUP;

    const int tid  = threadIdx.x;
    const int wave = tid >> 6;

    // ---- stage: async global->LDS, 16B/lane, each byte fetched once ----
    const int nfull = total & ~255;
    for (int base = 0; base < nfull; base += 256) {
        const int idx = base + tid;
        const int p   = idx >> 3;          // pixel (row-major in box)
        const int q   = idx & 7;           // float4 within slice
        const int py  = (int)(((unsigned)p * magic) >> 16);
        const int px  = p - py * rw;
        const float* src = src0 + ((size_t)((py << 6) + px)) * IMG_C + (q << 2);
        __builtin_amdgcn_global_load_lds(
            (as1_cvoid*)src,
            (as3_void*)&smem[base + (wave << 6)],  // wave-uniform base; lane*16 dest
            16, 0, 0);
    }
    // tail (partial chunk): plain load + LDS write
    for (int idx = nfull + tid; idx < total; idx += 256) {
        const int p  = idx >> 3;
        const int q  = idx & 7;
        const int py = (int)(((unsigned)p * magic) >> 16);
        const int px = p - py * rw;
        smem[idx] = ((const v4f*)(src0 + ((size_t)((py << 6) + px)) * IMG_C))[q];
    }
    __builtin_amdgcn_s_waitcnt(0);   // drain global_load_lds before LDS reads
    __syncthreads();

    // ---- compute: 49 cells x 8 quads from LDS ----
    const int q    = tid & (NQUAD - 1);  // float4 within slice (fastest -> coalesced)
    const int slot = tid >> 3;           // 32 cell slots

    const float inv7 = 1.0f / 7.0f;
    const float scx  = (float)rw * inv7;
    const float scy  = (float)rh * inv7;

    v4f* out4 = (v4f*)out + (size_t)r * (POOLSZ * POOLSZ) * (IMG_C / 4)
                + g * NQUAD + q;

#pragma unroll
    for (int it = 0; it < 2; ++it) {
        const int cell = it * 32 + slot;
        if (cell < POOLSZ * POOLSZ) {
            const int cy = cell / POOLSZ;        // compile-time magic div
            const int cx = cell - cy * POOLSZ;

            // src = (p+0.5)*size/7 - 0.5; lerp from unclipped floor (ref semantics)
            const float srcy = ((float)cy + 0.5f) * scy - 0.5f;
            const float fy   = floorf(srcy);
            const float ty   = srcy - fy;
            const int   iy   = (int)fy;
            const int   y0   = min(max(iy,     0), rh - 1);
            const int   y1   = min(max(iy + 1, 0), rh - 1);

            const float srcx = ((float)cx + 0.5f) * scx - 0.5f;
            const float fx   = floorf(srcx);
            const float tx   = srcx - fx;
            const int   ix   = (int)fx;
            const int   x0   = min(max(ix,     0), rw - 1);
            const int   x1   = min(max(ix + 1, 0), rw - 1);

            const v4f a = smem[(y0 * rw + x0) * NQUAD + q];
            const v4f b = smem[(y0 * rw + x1) * NQUAD + q];
            const v4f c = smem[(y1 * rw + x0) * NQUAD + q];
            const v4f d = smem[(y1 * rw + x1) * NQUAD + q];

            const v4f top = a + (b - a) * tx;
            const v4f bot = c + (d - c) * tx;
            const v4f o   = top + (bot - top) * ty;
            out4[(size_t)cell * (IMG_C / 4)] = o;   // plain store
        }
    }
}

extern "C" void kernel_launch(void* const* d_in, const int* in_sizes, int n_in,
                              void* d_out, int out_size, void* d_ws, size_t ws_size,
                              hipStream_t stream) {
    const float* img  = (const float*)d_in[0];
    const int*   rois = (const int*)d_in[1];
    float*       out  = (float*)d_out;
    const int R = in_sizes[1] / 4;            // rois: (1, R, 4)
    const int n_blocks = R * NGROUP;          // 1024*32 = 32768
    const int roisPerXcd = (R % NUM_XCD == 0) ? (R / NUM_XCD) : 0;
    roi_pool_lds32_kernel<<<n_blocks, 256, 0, stream>>>(img, rois, out, roisPerXcd);
}